// Round 1
// baseline (192.431 us; speedup 1.0000x reference)
//
#include <hip/hip_runtime.h>
#include <hip/hip_bf16.h>

// Problem constants (from reference)
constexpr int B   = 16;
constexpr int P   = 87;
constexpr int K   = 4;
constexpr int N   = 32768;
constexpr int D   = 256;
constexpr int HID = 128;
constexpr int CH  = 64;          // chunks per batch for attn_pool
constexpr int CHN = N / CH;      // 512 rows per chunk
constexpr float SCL = 0.125f;    // ATTN_SCALE / TAU = (1/16)/0.5

// ---------------------------------------------------------------------------
// Kernel 1b: q = object_queries @ Wq + bq   (B*K rows of D outputs)
// ---------------------------------------------------------------------------
__global__ __launch_bounds__(256) void qproj(const float* __restrict__ oq,
                                             const float* __restrict__ Wq,
                                             const float* __restrict__ bq,
                                             float* __restrict__ q) {
    const int row = blockIdx.x;       // 0..B*K-1
    const int j   = threadIdx.x;      // 0..D-1
    const float* x = oq + (size_t)row * D;
    float acc = bq[j];
    for (int i = 0; i < D; ++i) {
        acc = fmaf(x[i], Wq[(size_t)i * D + j], acc);  // x[i] uniform -> s_load
    }
    q[(size_t)row * D + j] = acc;
}

// ---------------------------------------------------------------------------
// Kernel 2: temperature-scaled attention pooling over N points.
// One wave processes one feats row per iteration (coalesced 1KB wave load).
// Writes per-block partials (sum_e, sum_e*x, sum_e*y, sum_e*z) per k.
// ---------------------------------------------------------------------------
__global__ __launch_bounds__(256) void attn_pool(const float* __restrict__ feats,
                                                 const float* __restrict__ xyz,
                                                 const float* __restrict__ q,
                                                 float* __restrict__ part) {
    __shared__ float sxyz[CHN * 3];            // 6 KB
    __shared__ float red[4][K * 4];

    const int b    = blockIdx.y;
    const int ch   = blockIdx.x;
    const int tid  = threadIdx.x;
    const int lane = tid & 63;
    const int w    = tid >> 6;                 // wave id 0..3

    // stage this chunk's xyz into LDS (coalesced)
    const float* xsrc = xyz + ((size_t)b * N + (size_t)ch * CHN) * 3;
    for (int i = tid; i < CHN * 3; i += 256) sxyz[i] = xsrc[i];

    // per-lane q fragments: lane l holds cols [4l, 4l+4) of each of the K q rows
    float4 qv[K];
#pragma unroll
    for (int k = 0; k < K; ++k)
        qv[k] = *(const float4*)(q + (size_t)(b * K + k) * D + lane * 4);

    __syncthreads();

    const float* fbase = feats + ((size_t)b * N + (size_t)ch * CHN) * D + lane * 4;

    float s[K]  = {0.f, 0.f, 0.f, 0.f};
    float ax[K] = {0.f, 0.f, 0.f, 0.f};
    float ay[K] = {0.f, 0.f, 0.f, 0.f};
    float az[K] = {0.f, 0.f, 0.f, 0.f};

    // software prefetch: one row in flight ahead
    float4 f = *(const float4*)(fbase + (size_t)w * D);

    for (int i = w; i < CHN; i += 4) {
        float4 cur = f;
        const int nx = i + 4;
        if (nx < CHN) f = *(const float4*)(fbase + (size_t)nx * D);

        float d[K];
#pragma unroll
        for (int k = 0; k < K; ++k) {
            d[k] = cur.x * qv[k].x;
            d[k] = fmaf(cur.y, qv[k].y, d[k]);
            d[k] = fmaf(cur.z, qv[k].z, d[k]);
            d[k] = fmaf(cur.w, qv[k].w, d[k]);
        }
        // full-wave butterfly reduce; afterwards all lanes hold the row dot
#pragma unroll
        for (int k = 0; k < K; ++k) {
#pragma unroll
            for (int off = 32; off; off >>= 1) d[k] += __shfl_xor(d[k], off);
        }

        const float x = sxyz[i * 3 + 0];   // broadcast LDS reads
        const float y = sxyz[i * 3 + 1];
        const float z = sxyz[i * 3 + 2];
#pragma unroll
        for (int k = 0; k < K; ++k) {
            const float e = __expf(d[k] * SCL);
            s[k]  += e;
            ax[k] = fmaf(e, x, ax[k]);
            ay[k] = fmaf(e, y, ay[k]);
            az[k] = fmaf(e, z, az[k]);
        }
    }

    // combine the 4 waves (accumulators are lane-uniform within a wave)
    if (lane == 0) {
#pragma unroll
        for (int k = 0; k < K; ++k) {
            red[w][k * 4 + 0] = s[k];
            red[w][k * 4 + 1] = ax[k];
            red[w][k * 4 + 2] = ay[k];
            red[w][k * 4 + 3] = az[k];
        }
    }
    __syncthreads();
    if (tid < K * 4) {
        const float v = red[0][tid] + red[1][tid] + red[2][tid] + red[3][tid];
        part[((size_t)b * CH + ch) * (K * 4) + tid] = v;
    }
}

// ---------------------------------------------------------------------------
// Kernel 1a: human contact head. 2 rows per block.
// h = relu(hq @ W1 + b1); logit = h @ W2 + b2; prob = sigmoid(logit)
// ---------------------------------------------------------------------------
__global__ __launch_bounds__(128) void human_head(const float* __restrict__ hq,
                                                  const float* __restrict__ W1,
                                                  const float* __restrict__ b1,
                                                  const float* __restrict__ W2,
                                                  const float* __restrict__ b2,
                                                  float* __restrict__ out) {
    __shared__ float sred[2][2];
    const int j    = threadIdx.x;         // hidden unit 0..127
    const int row0 = blockIdx.x * 2;      // 696 blocks * 2 = 1392 rows exactly

    const float* x0 = hq + (size_t)row0 * D;
    const float* x1 = x0 + D;
    float acc0 = b1[j];
    float acc1 = acc0;
    for (int i = 0; i < D; ++i) {
        const float wv = W1[(size_t)i * HID + j];   // coalesced
        acc0 = fmaf(x0[i], wv, acc0);               // x*[i] uniform -> s_load
        acc1 = fmaf(x1[i], wv, acc1);
    }
    const float w2 = W2[j];
    float v0 = fmaxf(acc0, 0.f) * w2;
    float v1 = fmaxf(acc1, 0.f) * w2;
#pragma unroll
    for (int off = 32; off; off >>= 1) {
        v0 += __shfl_xor(v0, off);
        v1 += __shfl_xor(v1, off);
    }
    const int wv_ = j >> 6, lane = j & 63;
    if (lane == 0) { sred[wv_][0] = v0; sred[wv_][1] = v1; }
    __syncthreads();
    if (j == 0) {
        const float bb = b2[0];
        const float l0 = sred[0][0] + sred[1][0] + bb;
        const float l1 = sred[0][1] + sred[1][1] + bb;
        out[B * P + row0 + 0] = l0;                       // logits
        out[B * P + row0 + 1] = l1;
        out[row0 + 0] = 1.f / (1.f + __expf(-l0));        // probs
        out[row0 + 1] = 1.f / (1.f + __expf(-l1));
    }
}

// ---------------------------------------------------------------------------
// Kernel 3: reduce chunk partials -> object_coords = (sum e*xyz) / (sum e)
// ---------------------------------------------------------------------------
__global__ __launch_bounds__(192) void finalize(const float* __restrict__ part,
                                                float* __restrict__ out) {
    const int t = threadIdx.x;            // 0..B*K*3-1
    if (t >= B * K * 3) return;
    const int c  = t % 3;
    const int bk = t / 3;
    const int k  = bk % K;
    const int b  = bk / K;
    float S = 0.f, V = 0.f;
    for (int ch = 0; ch < CH; ++ch) {
        const float* p = part + (((size_t)b * CH + ch) * K + k) * 4;
        S += p[0];
        V += p[1 + c];
    }
    out[2 * B * P + (b * K + k) * 3 + c] = V / S;
}

// ---------------------------------------------------------------------------
extern "C" void kernel_launch(void* const* d_in, const int* in_sizes, int n_in,
                              void* d_out, int out_size, void* d_ws, size_t ws_size,
                              hipStream_t stream) {
    const float* hq    = (const float*)d_in[0];
    const float* oq    = (const float*)d_in[1];
    const float* feats = (const float*)d_in[2];
    const float* xyz   = (const float*)d_in[3];
    const float* W1    = (const float*)d_in[4];
    const float* b1    = (const float*)d_in[5];
    const float* W2    = (const float*)d_in[6];
    const float* b2    = (const float*)d_in[7];
    const float* Wq    = (const float*)d_in[8];
    const float* bq    = (const float*)d_in[9];
    float* out = (float*)d_out;

    float* q    = (float*)d_ws;               // B*K*D floats
    float* part = q + (size_t)B * K * D;      // B*CH*K*4 floats

    qproj<<<B * K, 256, 0, stream>>>(oq, Wq, bq, q);
    attn_pool<<<dim3(CH, B), 256, 0, stream>>>(feats, xyz, q, part);
    human_head<<<(B * P) / 2, 128, 0, stream>>>(hq, W1, b1, W2, b2, out);
    finalize<<<1, 192, 0, stream>>>(part, out);
}

// Round 2
// 136.643 us; speedup vs baseline: 1.4083x; 1.4083x over previous
//
#include <hip/hip_runtime.h>
#include <hip/hip_bf16.h>

typedef float f4 __attribute__((ext_vector_type(4)));

constexpr int B   = 16;
constexpr int P   = 87;
constexpr int K   = 4;
constexpr int N   = 32768;
constexpr int D   = 256;
constexpr int HID = 128;
constexpr int CH  = 64;          // chunks per batch
constexpr int CHN = N / CH;      // 512 rows per chunk
constexpr float SCL = 0.125f;    // ATTN_SCALE / TAU

constexpr int HB  = (B * P) / 4; // 348 human-head blocks (4 rows each)

// ---------------------------------------------------------------------------
// q = object_queries @ Wq + bq
// ---------------------------------------------------------------------------
__global__ __launch_bounds__(256) void qproj(const float* __restrict__ oq,
                                             const float* __restrict__ Wq,
                                             const float* __restrict__ bq,
                                             float* __restrict__ q) {
    const int row = blockIdx.x;       // 0..B*K-1
    const int j   = threadIdx.x;      // 0..D-1
    const float* x = oq + (size_t)row * D;
    float a0 = bq[j], a1 = 0.f, a2 = 0.f, a3 = 0.f;
#pragma unroll 4
    for (int i = 0; i < D; i += 4) {
        a0 = fmaf(x[i + 0], Wq[(size_t)(i + 0) * D + j], a0);
        a1 = fmaf(x[i + 1], Wq[(size_t)(i + 1) * D + j], a1);
        a2 = fmaf(x[i + 2], Wq[(size_t)(i + 2) * D + j], a2);
        a3 = fmaf(x[i + 3], Wq[(size_t)(i + 3) * D + j], a3);
    }
    q[(size_t)row * D + j] = (a0 + a1) + (a2 + a3);
}

// ---------------------------------------------------------------------------
// Fused big kernel: blocks [0, HB) = human head, blocks [HB, HB+B*CH) = attn.
// Human first so its work hides under the BW-bound attention phase.
// ---------------------------------------------------------------------------
__global__ __launch_bounds__(256) void fused_main(const float* __restrict__ feats,
                                                  const float* __restrict__ xyz,
                                                  const float* __restrict__ q,
                                                  const float* __restrict__ hq,
                                                  const float* __restrict__ W1,
                                                  const float* __restrict__ b1,
                                                  const float* __restrict__ W2,
                                                  const float* __restrict__ b2,
                                                  float* __restrict__ part,
                                                  float* __restrict__ out) {
    __shared__ float sxyz[CHN * 3];            // 6 KB
    __shared__ float red[4][K * 4];
    __shared__ float sred[2][2][2];            // [row-pair][wave-half][row]

    const int bid = blockIdx.x;
    const int tid = threadIdx.x;

    if (bid < HB) {
        // ---------------- human contact head: 4 rows per block --------------
        const int j    = tid & (HID - 1);          // hidden unit 0..127
        const int rp   = tid >> 7;                 // 0/1 -> row pair
        const int row0 = bid * 4 + rp * 2;

        const float* x0 = hq + (size_t)row0 * D;
        const float* x1 = x0 + D;
        float acc0 = b1[j];
        float acc1 = acc0;
#pragma unroll 4
        for (int i = 0; i < D; ++i) {
            const float wv = W1[(size_t)i * HID + j];   // coalesced
            acc0 = fmaf(x0[i], wv, acc0);               // x*[i] uniform
            acc1 = fmaf(x1[i], wv, acc1);
        }
        const float w2 = W2[j];
        float v0 = fmaxf(acc0, 0.f) * w2;
        float v1 = fmaxf(acc1, 0.f) * w2;
#pragma unroll
        for (int off = 32; off; off >>= 1) {
            v0 += __shfl_xor(v0, off);
            v1 += __shfl_xor(v1, off);
        }
        const int lane = tid & 63;
        const int wh   = (tid >> 6) & 1;           // which half of the 128-thr pair
        if (lane == 0) { sred[rp][wh][0] = v0; sred[rp][wh][1] = v1; }
        __syncthreads();
        if (tid < 2) {                             // tid = row pair
            const float bb = b2[0];
            const float l0 = sred[tid][0][0] + sred[tid][1][0] + bb;
            const float l1 = sred[tid][0][1] + sred[tid][1][1] + bb;
            const int r = bid * 4 + tid * 2;
            out[B * P + r + 0] = l0;
            out[B * P + r + 1] = l1;
            out[r + 0] = 1.f / (1.f + __expf(-l0));
            out[r + 1] = 1.f / (1.f + __expf(-l1));
        }
        return;
    }

    // ------------------------ attention pooling -----------------------------
    const int abid = bid - HB;
    const int b    = abid >> 6;                // batch
    const int ch   = abid & 63;                // chunk
    const int lane = tid & 63;
    const int w    = tid >> 6;                 // wave 0..3
    const int sg   = lane >> 4;                // subgroup (row slot) 0..3
    const int m    = lane & 15;                // 16-lane index

    // stage this chunk's xyz into LDS (coalesced)
    const float* xsrc = xyz + ((size_t)b * N + (size_t)ch * CHN) * 3;
    for (int i = tid; i < CHN * 3; i += 256) sxyz[i] = xsrc[i];

    // q fragments: lane m holds cols [16m, 16m+16) of each of the K q rows
    f4 qv[K][4];
#pragma unroll
    for (int k = 0; k < K; ++k)
#pragma unroll
        for (int j = 0; j < 4; ++j)
            qv[k][j] = *(const f4*)(q + (size_t)(b * K + k) * D + m * 16 + j * 4);

    __syncthreads();

    const float* fbase = feats + ((size_t)b * N + (size_t)ch * CHN) * D;

    float s_[K] = {0.f, 0.f, 0.f, 0.f};
    float ax[K] = {0.f, 0.f, 0.f, 0.f};
    float ay[K] = {0.f, 0.f, 0.f, 0.f};
    float az[K] = {0.f, 0.f, 0.f, 0.f};

    // wave w handles 4-row groups g = w, w+4, ... ; subgroup sg owns row 4g+sg
    for (int g = w; g < CHN / 4; g += 4) {
        const int r = g * 4 + sg;
        const float* rp = fbase + (size_t)r * D + m * 16;
        f4 f0 = *(const f4*)(rp + 0);
        f4 f1 = *(const f4*)(rp + 4);
        f4 f2 = *(const f4*)(rp + 8);
        f4 f3 = *(const f4*)(rp + 12);

        float d[K];
#pragma unroll
        for (int k = 0; k < K; ++k) {
            float t0 = f0.x * qv[k][0].x;
            t0 = fmaf(f0.y, qv[k][0].y, t0);
            t0 = fmaf(f0.z, qv[k][0].z, t0);
            t0 = fmaf(f0.w, qv[k][0].w, t0);
            float t1 = f1.x * qv[k][1].x;
            t1 = fmaf(f1.y, qv[k][1].y, t1);
            t1 = fmaf(f1.z, qv[k][1].z, t1);
            t1 = fmaf(f1.w, qv[k][1].w, t1);
            t0 = fmaf(f2.x, qv[k][2].x, t0);
            t0 = fmaf(f2.y, qv[k][2].y, t0);
            t0 = fmaf(f2.z, qv[k][2].z, t0);
            t0 = fmaf(f2.w, qv[k][2].w, t0);
            t1 = fmaf(f3.x, qv[k][3].x, t1);
            t1 = fmaf(f3.y, qv[k][3].y, t1);
            t1 = fmaf(f3.z, qv[k][3].z, t1);
            t1 = fmaf(f3.w, qv[k][3].w, t1);
            d[k] = t0 + t1;
        }
        // reduce within the 16-lane subgroup (4 steps, amortized over 4 rows)
#pragma unroll
        for (int k = 0; k < K; ++k) {
            float v = d[k];
            v += __shfl_xor(v, 8);
            v += __shfl_xor(v, 4);
            v += __shfl_xor(v, 2);
            v += __shfl_xor(v, 1);
            d[k] = v;
        }

        const float x = sxyz[r * 3 + 0];
        const float y = sxyz[r * 3 + 1];
        const float z = sxyz[r * 3 + 2];
#pragma unroll
        for (int k = 0; k < K; ++k) {
            const float e = __expf(d[k] * SCL);
            s_[k] += e;
            ax[k] = fmaf(e, x, ax[k]);
            ay[k] = fmaf(e, y, ay[k]);
            az[k] = fmaf(e, z, az[k]);
        }
    }

    // combine the 4 subgroups (xor 16, 32), then the 4 waves via LDS
#pragma unroll
    for (int k = 0; k < K; ++k) {
        float v;
        v = s_[k]; v += __shfl_xor(v, 16); v += __shfl_xor(v, 32); s_[k] = v;
        v = ax[k]; v += __shfl_xor(v, 16); v += __shfl_xor(v, 32); ax[k] = v;
        v = ay[k]; v += __shfl_xor(v, 16); v += __shfl_xor(v, 32); ay[k] = v;
        v = az[k]; v += __shfl_xor(v, 16); v += __shfl_xor(v, 32); az[k] = v;
    }
    if (lane == 0) {
#pragma unroll
        for (int k = 0; k < K; ++k) {
            red[w][k * 4 + 0] = s_[k];
            red[w][k * 4 + 1] = ax[k];
            red[w][k * 4 + 2] = ay[k];
            red[w][k * 4 + 3] = az[k];
        }
    }
    __syncthreads();
    if (tid < K * 4) {
        const float v = red[0][tid] + red[1][tid] + red[2][tid] + red[3][tid];
        part[((size_t)b * CH + ch) * (K * 4) + tid] = v;
    }
}

// ---------------------------------------------------------------------------
// reduce chunk partials -> object_coords
// ---------------------------------------------------------------------------
__global__ __launch_bounds__(192) void finalize(const float* __restrict__ part,
                                                float* __restrict__ out) {
    const int t = threadIdx.x;
    if (t >= B * K * 3) return;
    const int c  = t % 3;
    const int bk = t / 3;
    const int k  = bk % K;
    const int b  = bk / K;
    float S = 0.f, V = 0.f;
    for (int ch = 0; ch < CH; ++ch) {
        const float* p = part + (((size_t)b * CH + ch) * K + k) * 4;
        S += p[0];
        V += p[1 + c];
    }
    out[2 * B * P + (b * K + k) * 3 + c] = V / S;
}

// ---------------------------------------------------------------------------
extern "C" void kernel_launch(void* const* d_in, const int* in_sizes, int n_in,
                              void* d_out, int out_size, void* d_ws, size_t ws_size,
                              hipStream_t stream) {
    const float* hq    = (const float*)d_in[0];
    const float* oq    = (const float*)d_in[1];
    const float* feats = (const float*)d_in[2];
    const float* xyz   = (const float*)d_in[3];
    const float* W1    = (const float*)d_in[4];
    const float* b1    = (const float*)d_in[5];
    const float* W2    = (const float*)d_in[6];
    const float* b2    = (const float*)d_in[7];
    const float* Wq    = (const float*)d_in[8];
    const float* bq    = (const float*)d_in[9];
    float* out = (float*)d_out;

    float* q    = (float*)d_ws;               // B*K*D floats
    float* part = q + (size_t)B * K * D;      // B*CH*K*4 floats

    qproj<<<B * K, 256, 0, stream>>>(oq, Wq, bq, q);
    fused_main<<<HB + B * CH, 256, 0, stream>>>(feats, xyz, q, hq, W1, b1, W2, b2,
                                                part, out);
    finalize<<<1, 192, 0, stream>>>(part, out);
}

// Round 3
// 109.380 us; speedup vs baseline: 1.7593x; 1.2492x over previous
//
#include <hip/hip_runtime.h>
#include <hip/hip_bf16.h>

typedef float f4 __attribute__((ext_vector_type(4)));

constexpr int B   = 16;
constexpr int P   = 87;
constexpr int K   = 4;
constexpr int N   = 32768;
constexpr int D   = 256;
constexpr int HID = 128;
constexpr int CH  = 128;         // chunks per batch
constexpr int CHN = N / CH;      // 256 rows per chunk
constexpr float SCL = 0.125f;    // ATTN_SCALE / TAU

constexpr int HB  = (B * P) / 4; // 348 human-head blocks (4 rows each)

__device__ __forceinline__ f4 ntload(const float* p) {
    return __builtin_nontemporal_load((const f4*)p);
}

// ---------------------------------------------------------------------------
// q = object_queries @ Wq + bq
// ---------------------------------------------------------------------------
__global__ __launch_bounds__(256) void qproj(const float* __restrict__ oq,
                                             const float* __restrict__ Wq,
                                             const float* __restrict__ bq,
                                             float* __restrict__ q) {
    const int row = blockIdx.x;       // 0..B*K-1
    const int j   = threadIdx.x;      // 0..D-1
    const float* x = oq + (size_t)row * D;
    float a0 = bq[j], a1 = 0.f, a2 = 0.f, a3 = 0.f;
#pragma unroll 4
    for (int i = 0; i < D; i += 4) {
        a0 = fmaf(x[i + 0], Wq[(size_t)(i + 0) * D + j], a0);
        a1 = fmaf(x[i + 1], Wq[(size_t)(i + 1) * D + j], a1);
        a2 = fmaf(x[i + 2], Wq[(size_t)(i + 2) * D + j], a2);
        a3 = fmaf(x[i + 3], Wq[(size_t)(i + 3) * D + j], a3);
    }
    q[(size_t)row * D + j] = (a0 + a1) + (a2 + a3);
}

// ---------------------------------------------------------------------------
// Fused big kernel: blocks [0, HB) = human head, blocks [HB, HB+B*CH) = attn.
// ---------------------------------------------------------------------------
__global__ __launch_bounds__(256) void fused_main(const float* __restrict__ feats,
                                                  const float* __restrict__ xyz,
                                                  const float* __restrict__ q,
                                                  const float* __restrict__ hq,
                                                  const float* __restrict__ W1,
                                                  const float* __restrict__ b1,
                                                  const float* __restrict__ W2,
                                                  const float* __restrict__ b2,
                                                  float* __restrict__ part,
                                                  float* __restrict__ out) {
    __shared__ float sxyz[CHN * 3];            // 3 KB
    __shared__ float red[4][K * 4];
    __shared__ float sred[2][2][2];

    const int bid = blockIdx.x;
    const int tid = threadIdx.x;

    if (bid < HB) {
        // ---------------- human contact head: 4 rows per block --------------
        const int j    = tid & (HID - 1);
        const int rp   = tid >> 7;
        const int row0 = bid * 4 + rp * 2;

        const float* x0 = hq + (size_t)row0 * D;
        const float* x1 = x0 + D;
        float acc0 = b1[j];
        float acc1 = acc0;
#pragma unroll 4
        for (int i = 0; i < D; ++i) {
            const float wv = W1[(size_t)i * HID + j];
            acc0 = fmaf(x0[i], wv, acc0);
            acc1 = fmaf(x1[i], wv, acc1);
        }
        const float w2 = W2[j];
        float v0 = fmaxf(acc0, 0.f) * w2;
        float v1 = fmaxf(acc1, 0.f) * w2;
#pragma unroll
        for (int off = 32; off; off >>= 1) {
            v0 += __shfl_xor(v0, off);
            v1 += __shfl_xor(v1, off);
        }
        const int lane = tid & 63;
        const int wh   = (tid >> 6) & 1;
        if (lane == 0) { sred[rp][wh][0] = v0; sred[rp][wh][1] = v1; }
        __syncthreads();
        if (tid < 2) {
            const float bb = b2[0];
            const float l0 = sred[tid][0][0] + sred[tid][1][0] + bb;
            const float l1 = sred[tid][0][1] + sred[tid][1][1] + bb;
            const int r = bid * 4 + tid * 2;
            out[B * P + r + 0] = l0;
            out[B * P + r + 1] = l1;
            out[r + 0] = 1.f / (1.f + __expf(-l0));
            out[r + 1] = 1.f / (1.f + __expf(-l1));
        }
        return;
    }

    // ------------------------ attention pooling -----------------------------
    const int abid = bid - HB;
    const int b    = abid >> 7;                // batch
    const int ch   = abid & (CH - 1);          // chunk
    const int lane = tid & 63;
    const int w    = tid >> 6;                 // wave 0..3
    const int sg   = lane >> 4;                // subgroup (row slot) 0..3
    const int m    = lane & 15;                // 16-lane index

    // stage this chunk's xyz into LDS (coalesced)
    const float* xsrc = xyz + ((size_t)b * N + (size_t)ch * CHN) * 3;
    for (int i = tid; i < CHN * 3; i += 256) sxyz[i] = xsrc[i];

    // q fragments: lane m holds cols {j*64 + 4m .. +4} for j=0..3, per k.
    // Matches the dense per-instruction feats layout below.
    f4 qv[K][4];
#pragma unroll
    for (int k = 0; k < K; ++k)
#pragma unroll
        for (int j = 0; j < 4; ++j)
            qv[k][j] = *(const f4*)(q + (size_t)(b * K + k) * D + j * 64 + m * 4);

    __syncthreads();

    const float* fbase = feats + ((size_t)b * N + (size_t)ch * CHN) * D;

    float s_[K] = {0.f, 0.f, 0.f, 0.f};
    float ax[K] = {0.f, 0.f, 0.f, 0.f};
    float ay[K] = {0.f, 0.f, 0.f, 0.f};
    float az[K] = {0.f, 0.f, 0.f, 0.f};

    constexpr int NG = CHN / 4;                // 64 row-groups per chunk

    // each load instruction covers 4 rows x dense 256B segments
    f4 f0, f1, f2, f3;
    {
        const float* rp = fbase + (size_t)(w * 4 + sg) * D + m * 4;
        f0 = ntload(rp + 0);
        f1 = ntload(rp + 64);
        f2 = ntload(rp + 128);
        f3 = ntload(rp + 192);
    }

    for (int g = w; g < NG; g += 4) {
        const f4 c0 = f0, c1 = f1, c2 = f2, c3 = f3;
        const int gn = g + 4;
        if (gn < NG) {                          // prefetch next group
            const float* rp = fbase + (size_t)(gn * 4 + sg) * D + m * 4;
            f0 = ntload(rp + 0);
            f1 = ntload(rp + 64);
            f2 = ntload(rp + 128);
            f3 = ntload(rp + 192);
        }
        const int r = g * 4 + sg;

        float d[K];
#pragma unroll
        for (int k = 0; k < K; ++k) {
            float t0 = c0.x * qv[k][0].x;
            t0 = fmaf(c0.y, qv[k][0].y, t0);
            t0 = fmaf(c0.z, qv[k][0].z, t0);
            t0 = fmaf(c0.w, qv[k][0].w, t0);
            float t1 = c1.x * qv[k][1].x;
            t1 = fmaf(c1.y, qv[k][1].y, t1);
            t1 = fmaf(c1.z, qv[k][1].z, t1);
            t1 = fmaf(c1.w, qv[k][1].w, t1);
            t0 = fmaf(c2.x, qv[k][2].x, t0);
            t0 = fmaf(c2.y, qv[k][2].y, t0);
            t0 = fmaf(c2.z, qv[k][2].z, t0);
            t0 = fmaf(c2.w, qv[k][2].w, t0);
            t1 = fmaf(c3.x, qv[k][3].x, t1);
            t1 = fmaf(c3.y, qv[k][3].y, t1);
            t1 = fmaf(c3.z, qv[k][3].z, t1);
            t1 = fmaf(c3.w, qv[k][3].w, t1);
            d[k] = t0 + t1;
        }
#pragma unroll
        for (int k = 0; k < K; ++k) {
            float v = d[k];
            v += __shfl_xor(v, 8);
            v += __shfl_xor(v, 4);
            v += __shfl_xor(v, 2);
            v += __shfl_xor(v, 1);
            d[k] = v;
        }

        const float x = sxyz[r * 3 + 0];
        const float y = sxyz[r * 3 + 1];
        const float z = sxyz[r * 3 + 2];
#pragma unroll
        for (int k = 0; k < K; ++k) {
            const float e = __expf(d[k] * SCL);
            s_[k] += e;
            ax[k] = fmaf(e, x, ax[k]);
            ay[k] = fmaf(e, y, ay[k]);
            az[k] = fmaf(e, z, az[k]);
        }
    }

    // combine the 4 subgroups, then the 4 waves via LDS
#pragma unroll
    for (int k = 0; k < K; ++k) {
        float v;
        v = s_[k]; v += __shfl_xor(v, 16); v += __shfl_xor(v, 32); s_[k] = v;
        v = ax[k]; v += __shfl_xor(v, 16); v += __shfl_xor(v, 32); ax[k] = v;
        v = ay[k]; v += __shfl_xor(v, 16); v += __shfl_xor(v, 32); ay[k] = v;
        v = az[k]; v += __shfl_xor(v, 16); v += __shfl_xor(v, 32); az[k] = v;
    }
    if (lane == 0) {
#pragma unroll
        for (int k = 0; k < K; ++k) {
            red[w][k * 4 + 0] = s_[k];
            red[w][k * 4 + 1] = ax[k];
            red[w][k * 4 + 2] = ay[k];
            red[w][k * 4 + 3] = az[k];
        }
    }
    __syncthreads();
    if (tid < K * 4) {
        const float v = red[0][tid] + red[1][tid] + red[2][tid] + red[3][tid];
        part[((size_t)b * CH + ch) * (K * 4) + tid] = v;
    }
}

// ---------------------------------------------------------------------------
// reduce chunk partials -> object_coords
// ---------------------------------------------------------------------------
__global__ __launch_bounds__(192) void finalize(const float* __restrict__ part,
                                                float* __restrict__ out) {
    const int t = threadIdx.x;
    if (t >= B * K * 3) return;
    const int c  = t % 3;
    const int bk = t / 3;
    const int k  = bk % K;
    const int b  = bk / K;
    float S = 0.f, V = 0.f;
    for (int ch = 0; ch < CH; ++ch) {
        const float* p = part + (((size_t)b * CH + ch) * K + k) * 4;
        S += p[0];
        V += p[1 + c];
    }
    out[2 * B * P + (b * K + k) * 3 + c] = V / S;
}

// ---------------------------------------------------------------------------
extern "C" void kernel_launch(void* const* d_in, const int* in_sizes, int n_in,
                              void* d_out, int out_size, void* d_ws, size_t ws_size,
                              hipStream_t stream) {
    const float* hq    = (const float*)d_in[0];
    const float* oq    = (const float*)d_in[1];
    const float* feats = (const float*)d_in[2];
    const float* xyz   = (const float*)d_in[3];
    const float* W1    = (const float*)d_in[4];
    const float* b1    = (const float*)d_in[5];
    const float* W2    = (const float*)d_in[6];
    const float* b2    = (const float*)d_in[7];
    const float* Wq    = (const float*)d_in[8];
    const float* bq    = (const float*)d_in[9];
    float* out = (float*)d_out;

    float* q    = (float*)d_ws;               // B*K*D floats
    float* part = q + (size_t)B * K * D;      // B*CH*K*4 floats

    qproj<<<B * K, 256, 0, stream>>>(oq, Wq, bq, q);
    fused_main<<<HB + B * CH, 256, 0, stream>>>(feats, xyz, q, hq, W1, b1, W2, b2,
                                                part, out);
    finalize<<<1, 192, 0, stream>>>(part, out);
}